// Round 14
// baseline (197.528 us; speedup 1.0000x reference)
//
#include <hip/hip_runtime.h>
#include <hip/hip_bf16.h>
#include <stdint.h>

#define B_   4
#define T_   2048
#define H_   8
#define HD_  64
#define DM_  512
#define N3_  1536

typedef short bf_el;
typedef __attribute__((ext_vector_type(8))) bf_el bfrag;   // 8 bf16 = 4 VGPRs
typedef __attribute__((ext_vector_type(4))) bf_el bhalf4;  // 4 bf16 = 2 VGPRs
typedef __attribute__((ext_vector_type(4))) float ffrag;

#define SCALE_L2E  0.18033688011112043f   /* 0.125 * log2(e) */
#define MASK_L2E   14426.950408889634f    /* 1e4  * log2(e) */

static __device__ __forceinline__ unsigned short f2bf(float f) {      // RNE
    union { float f; unsigned int i; } v; v.f = f;
    unsigned int r = v.i + 0x7fff + ((v.i >> 16) & 1);
    return (unsigned short)(r >> 16);
}
static __device__ __forceinline__ unsigned short f2bf_fast(float f) { // round-half-up
    union { float f; unsigned int i; } v; v.f = f;
    return (unsigned short)((v.i + 0x8000u) >> 16);
}

// pack 2 f32 -> 2 bf16 (RNE), lo16=a, hi16=b  [gfx950-verified: learn_hip m240]
static __device__ __forceinline__ unsigned int cvt_pk_bf16(float a, float b) {
    unsigned int r;
    asm("v_cvt_pk_bf16_f32 %0, %1, %2" : "=v"(r) : "v"(a), "v"(b));
    return r;
}

// async global->LDS, 16B per lane; LDS dest = wave-uniform base + lane*16
typedef __attribute__((address_space(1))) const unsigned int gu32;
typedef __attribute__((address_space(3))) unsigned int lu32;
static __device__ __forceinline__ void glds16(const unsigned short* g, unsigned short* l) {
    __builtin_amdgcn_global_load_lds((gu32*)g, (lu32*)l, 16, 0, 0);
}

// counted vmcnt wait (keeps newest N vm ops in flight) + scheduler fence
#define VMCNT(n) do { asm volatile("s_waitcnt vmcnt(" #n ")" ::: "memory"); \
                      __builtin_amdgcn_sched_barrier(0); } while (0)

// ---------------------------------------------------------------------------
// Kernel 0 (prep, 2 BW-bound roles by blockIdx.x; mask scan moved to k_gemm):
//  [0,256)  : X fp32 -> bf16
//  [256,448): W [512,1536] fp32 -> Wt bf16 [1536,512]
// ---------------------------------------------------------------------------
__global__ __launch_bounds__(256) void k_prep(const float* __restrict__ W,
                                              const float* __restrict__ X,
                                              unsigned short* __restrict__ Wt,
                                              unsigned short* __restrict__ Xb) {
    __shared__ __align__(16) unsigned short Ls[64 * 72];
    const int bid = blockIdx.x;
    const int tid = threadIdx.x;

    if (bid < 256) {
        // ---- X convert: 16384 floats per block ----
        const float* src = X + (size_t)bid * 16384;
        unsigned short* dst = Xb + (size_t)bid * 16384;
#pragma unroll
        for (int j = 0; j < 8; ++j) {
            int idx = j * 512 + tid * 2;
            float4 f0 = *(const float4*)(src + idx * 4);
            float4 f1 = *(const float4*)(src + idx * 4 + 4);
            __align__(16) unsigned short t8[8];
            t8[0] = f2bf_fast(f0.x); t8[1] = f2bf_fast(f0.y);
            t8[2] = f2bf_fast(f0.z); t8[3] = f2bf_fast(f0.w);
            t8[4] = f2bf_fast(f1.x); t8[5] = f2bf_fast(f1.y);
            t8[6] = f2bf_fast(f1.z); t8[7] = f2bf_fast(f1.w);
            *(uint4*)(dst + idx * 4) = *(const uint4*)t8;
        }
        return;
    }
    // ---- W transpose+convert ----
    {
        const int t  = bid - 256;                 // 0..191 = 24 x 8
        const int n0 = (t % 24) * 64;
        const int k0 = (t / 24) * 64;
#pragma unroll
        for (int i = 0; i < 4; ++i) {
            int chunk = tid + i * 256;
            int k = chunk >> 4;
            int c = chunk & 15;
            float4 f = *(const float4*)(W + (size_t)(k0 + k) * N3_ + n0 + c * 4);
            unsigned short* p = Ls + k * 72 + c * 4;
            p[0] = f2bf(f.x); p[1] = f2bf(f.y); p[2] = f2bf(f.z); p[3] = f2bf(f.w);
        }
        __syncthreads();
        const int n = tid >> 2;
        const int g = tid & 3;
        __align__(16) unsigned short tmp[16];
#pragma unroll
        for (int i = 0; i < 16; ++i) tmp[i] = Ls[(g * 16 + i) * 72 + n];
        uint4* dst = (uint4*)(Wt + (size_t)(n0 + n) * DM_ + k0 + g * 16);
        dst[0] = *(const uint4*)(tmp);
        dst[1] = *(const uint4*)(tmp + 8);
    }
}

// ---------------------------------------------------------------------------
// Kernel 1 (grid 1024, role-interleaved in groups of 16 so both roles stripe
// across all 8 XCDs and each CU co-hosts ~1 gemm + 1 mask block):
//  role 0 (sub 0..511): QKV GEMM tile — EXACT round-13 ring-4 schedule.
//  role 1 (sub 0..511): mask scan (BW-only, needed only by k_attn) — hides
//    its 67 MB HBM stream under the gemm blocks' MFMA time.
//    flags = per-(b,qt64) x 4 quarter-words, byte w written exclusively by
//    wave w of quarter-block (sub&3): plain stores, no atomics, no memset.
// gemm XCD locality preserved: XCD = bid%8 = sub%8 = mt%8.
// ---------------------------------------------------------------------------
__global__ __launch_bounds__(256) void k_gemm_qkv(const unsigned short* __restrict__ Xb,
                                                  const unsigned short* __restrict__ Wt,
                                                  const float* __restrict__ bias,
                                                  unsigned short* __restrict__ Qb,
                                                  unsigned short* __restrict__ Kb,
                                                  unsigned short* __restrict__ Vtb,
                                                  const float* __restrict__ mask,
                                                  int* __restrict__ flags) {
    // ring-4: buf b at SH + b*10240 (A 4096 shorts, then B 6144 shorts).
    // epilogue Cs (64x200 = 12800 shorts) reuses the front.
    __shared__ __align__(16) unsigned short SH[40960];
    unsigned short* Cs = SH;            // row stride 200 shorts (192 data + 8 pad)

    const int bid  = blockIdx.x;
    const int tid  = threadIdx.x;
    const int role = (bid >> 4) & 1;
    const int sub  = ((bid >> 5) << 4) | (bid & 15);   // 0..511 per role

    if (role) {
        // ---- mask scan: 16 consecutive mask rows per block (128 KB) ----
        const int R0 = sub * 16;              // global row in [0, 8192)
        const int mb = R0 >> 11;              // batch
        const int q0m = R0 & 2047;
        const int e  = mb * 32 + (q0m >> 6);  // flag group (b*32 + qt64)
        const int wv = tid >> 6, lane = tid & 63;
        unsigned int acc = 0u;
        const float* base = mask + (size_t)R0 * T_ + tid * 8;
#pragma unroll
        for (int rr = 0; rr < 16; ++rr) {
            const uint4 u0 = *(const uint4*)(base + (size_t)rr * T_);
            const uint4 u1 = *(const uint4*)(base + (size_t)rr * T_ + 4);
            acc |= (u0.x ^ 0x3F800000u) | (u0.y ^ 0x3F800000u) |
                   (u0.z ^ 0x3F800000u) | (u0.w ^ 0x3F800000u) |
                   (u1.x ^ 0x3F800000u) | (u1.y ^ 0x3F800000u) |
                   (u1.z ^ 0x3F800000u) | (u1.w ^ 0x3F800000u);
        }
        unsigned long long bal = __ballot(acc != 0u);   // lane 8j..8j+7 = kt 8w+j
        if (lane == 0) {
            unsigned int byte = 0u;
#pragma unroll
            for (int j = 0; j < 8; ++j)
                if ((bal >> (8 * j)) & 0xFFULL) byte |= (1u << j);
            // word (e*4 + quarter), byte lane = wave  (bit kt = 8*wv + j)
            ((unsigned char*)flags)[((size_t)e * 4 + (sub & 3)) * 4 + wv] =
                (unsigned char)byte;
        }
        return;
    }

    const int wave = tid >> 6;
    const int lane = tid & 63;
    const int quad = lane >> 4;
    const int l16  = lane & 15;
    const int wm = wave >> 1, wn = wave & 1;    // 2x2 waves: 64 rows x 96 cols each
    const int h  = sub >> 6;                    // head
    const int m0 = (sub & 63) * 128;
    const int n0 = h * 192;

    float bvv[6];
#pragma unroll
    for (int ni = 0; ni < 6; ++ni) bvv[ni] = bias[n0 + wn * 96 + ni * 16 + l16];

    ffrag acc[4][6];
#pragma unroll
    for (int i = 0; i < 4; ++i)
#pragma unroll
        for (int j = 0; j < 6; ++j) acc[i][j] = (ffrag){0.f, 0.f, 0.f, 0.f};

    // staging geometry: lane l covers local row lrow=l>>2 of a 16-row slab,
    // slot (l&3); global col16 is pre-swizzled: slot ^ (lrow&3).
    const int lrow = lane >> 2;
    const int gslot = (lane & 3) ^ (lrow & 3);
    const unsigned short* Ag = Xb + (size_t)(m0 + wave * 32 + lrow) * DM_ + gslot * 8;
    const unsigned short* Bg = Wt + (size_t)(n0 + wave * 48 + lrow) * DM_ + gslot * 8;

    auto STAGE = [&](int buf, int kt) {
        unsigned short* AL = SH + buf * 10240 + wave * 1024;
        unsigned short* BL = SH + buf * 10240 + 4096 + wave * 1536;
        const unsigned short* ag = Ag + kt * 32;
        const unsigned short* bg = Bg + kt * 32;
        glds16(ag, AL);
        glds16(ag + (size_t)16 * DM_, AL + 512);
        glds16(bg, BL);
        glds16(bg + (size_t)16 * DM_, BL + 512);
        glds16(bg + (size_t)32 * DM_, BL + 1024);
    };

    STAGE(0, 0);
    STAGE(1, 1);

    for (int kt = 0; kt < 16; ++kt) {
        if (kt < 14) STAGE((kt + 2) & 3, kt + 2);
        if (kt < 14)      { VMCNT(10); }
        else if (kt == 14){ VMCNT(5); }
        else              { VMCNT(0); }
        __builtin_amdgcn_s_barrier();

        const unsigned short* As = SH + (kt & 3) * 10240;
        const unsigned short* Bs = As + 4096;
        // swizzled reads: row R, want col16=quad -> slot = quad ^ (R&3),
        // R&3 == l16&3 for all fragment rows.
        const int rslot = (quad ^ (l16 & 3)) * 8;
        bfrag af[4], bfr[6];
#pragma unroll
        for (int mi = 0; mi < 4; ++mi)
            af[mi] = *(const bfrag*)(As + (wm * 64 + mi * 16 + l16) * 32 + rslot);
#pragma unroll
        for (int ni = 0; ni < 6; ++ni)
            bfr[ni] = *(const bfrag*)(Bs + (wn * 96 + ni * 16 + l16) * 32 + rslot);
        __builtin_amdgcn_s_setprio(1);
#pragma unroll
        for (int mi = 0; mi < 4; ++mi)
#pragma unroll
            for (int ni = 0; ni < 6; ++ni)
                acc[mi][ni] = __builtin_amdgcn_mfma_f32_16x16x32_bf16(af[mi], bfr[ni], acc[mi][ni], 0, 0, 0);
        __builtin_amdgcn_s_setprio(0);
    }

    // epilogue: two 64-row halves through Cs, coalesced uint4 stores.
    // Q columns (c%3==0) pre-scaled by 0.125*log2(e) so attn softmax is bare exp2.
    const int b   = m0 >> 11;
    const int tb0 = m0 & 2047;
    const size_t bh = (size_t)(b * 8 + h);
    float cscale[6];
#pragma unroll
    for (int ni = 0; ni < 6; ++ni) {
        int c = wn * 96 + ni * 16 + l16;
        cscale[ni] = (c % 3 == 0) ? SCALE_L2E : 1.0f;
    }
#pragma unroll
    for (int half = 0; half < 2; ++half) {
        __syncthreads();
        if (wm == half) {
#pragma unroll
            for (int mi = 0; mi < 4; ++mi)
#pragma unroll
                for (int ni = 0; ni < 6; ++ni)
#pragma unroll
                    for (int reg = 0; reg < 4; ++reg) {
                        int r = mi * 16 + quad * 4 + reg;          // 0..63 in half
                        int c = wn * 96 + ni * 16 + l16;           // 0..191
                        Cs[r * 200 + c] = f2bf_fast((acc[mi][ni][reg] + bvv[ni]) * cscale[ni]);
                    }
        }
        __syncthreads();
        const int tb = tb0 + half * 64;
#pragma unroll
        for (int i = 0; i < 2; ++i) {
            int idx = tid + i * 256;            // 0..511
            int tl = idx >> 3, hc = (idx & 7) * 8;
            __align__(16) unsigned short tq[8], tk[8];
#pragma unroll
            for (int j = 0; j < 8; ++j) {
                tq[j] = Cs[tl * 200 + (hc + j) * 3 + 0];
                tk[j] = Cs[tl * 200 + (hc + j) * 3 + 1];
            }
            *(uint4*)(Qb + (bh * T_ + tb + tl) * HD_ + hc) = *(const uint4*)tq;
            *(uint4*)(Kb + (bh * T_ + tb + tl) * HD_ + hc) = *(const uint4*)tk;
        }
#pragma unroll
        for (int i = 0; i < 2; ++i) {
            int idx = tid + i * 256;
            int hd = idx >> 3, t8 = (idx & 7) * 8;
            __align__(16) unsigned short tv[8];
#pragma unroll
            for (int j = 0; j < 8; ++j)
                tv[j] = Cs[(t8 + j) * 200 + hd * 3 + 2];
            *(uint4*)(Vtb + (bh * HD_ + hd) * T_ + tb + t8) = *(const uint4*)tv;
        }
    }
}

// ---------------------------------------------------------------------------
// Kernel 2: flash attention — EXACT round-8/12/13 structure (proven 3x):
// RING of 4 buffers (64 KB), distance-2 prefetch, counted vmcnt:
//   iter kt: STAGE((kt+2)&3, kt+2); vmcnt(8); s_barrier; read buf kt&3.
// ---------------------------------------------------------------------------
__global__ __launch_bounds__(256, 2) void k_attn(const unsigned short* __restrict__ Q,
                                                 const unsigned short* __restrict__ K,
                                                 const unsigned short* __restrict__ Vt,
                                                 const float* __restrict__ mask,
                                                 const int* __restrict__ flags,
                                                 float* __restrict__ out) {
    // [K buf0..3 | V buf0..3], each 64x64 shorts (8KB), linear. 64 KB total;
    // epilogue reuses the front as 2 x (64 x 66) float scratch (33.8 KB).
    __shared__ __align__(16) unsigned short SH[32768];
    __shared__ float Rs[256];           // row sums [kh][128]

    const int tid = threadIdx.x;
    const int wave = tid >> 6, lane = tid & 63;
    const int quad = lane >> 4, l16 = lane & 15;
    const int rg = wave & 1;        // row group: q rows rg*64 .. rg*64+63
    const int kh = wave >> 1;       // kv half:  kv kh*32 .. kh*32+31
    const int bh = blockIdx.x & 31, b = bh >> 3, h = bh & 7;
    const int qt = blockIdx.x >> 5;      // 0..15
    const int q0 = qt * 128;

    // Q fragments: 4 groups of 16 rows (B-operand of swapped QK^T:
    // lane l16 = q col, k = ks*32 + quad*8 + j)
    bfrag qf[4][2];
#pragma unroll
    for (int g = 0; g < 4; ++g) {
        size_t qrow = ((size_t)bh * T_ + q0 + rg * 64 + g * 16 + l16) * HD_;
        qf[g][0] = *(const bfrag*)(Q + qrow + quad * 8);
        qf[g][1] = *(const bfrag*)(Q + qrow + 32 + quad * 8);
    }
    // of[g][0..3] = O accumulators; of[g][4] = row-sum via ones-MFMA.
    ffrag of[4][5];
#pragma unroll
    for (int g = 0; g < 4; ++g)
#pragma unroll
        for (int nb = 0; nb < 5; ++nb) of[g][nb] = (ffrag){0.f, 0.f, 0.f, 0.f};

    bfrag vones;
#pragma unroll
    for (int j = 0; j < 8; ++j) vones[j] = (short)0x3F80;   // bf16 1.0

    // flags: OR the 4 quarter-words of this (b, 64-row block)
    const int e = b * 32 + qt * 2 + rg;
    const int4 fw = *(const int4*)(flags + (size_t)e * 4);
    const unsigned int flbits = (unsigned int)(fw.x | fw.y | fw.z | fw.w);

    // ---- staging geometry (glds, pre-swizzled source) ----
    const int lrow = lane >> 3, lcol = lane & 7, swz = lcol ^ lrow;
    const int voffK = lrow * 64 + swz * 8;                    // shorts in 8-row seg
    const size_t voffV = (size_t)(wave * 16 + lrow) * T_ + swz * 8;
    const unsigned short* Kbh = K  + (size_t)bh * T_ * HD_;   // + kt*4096 per tile
    const unsigned short* Vbh = Vt + (size_t)bh * HD_ * T_;   // + kt*64 per tile

    auto STAGE = [&](int buf, int kt) {
        unsigned short* KL = &SH[buf * 4096] + wave * 1024;
        unsigned short* VL = &SH[16384 + buf * 4096] + wave * 1024;
        const unsigned short* kg = Kbh + (size_t)kt * 4096 + wave * 1024 + voffK;
        const unsigned short* vg = Vbh + (size_t)kt * 64 + voffV;
        glds16(kg, KL);
        glds16(kg + 512, KL + 512);
        glds16(vg, VL);
        glds16(vg + (size_t)8 * T_, VL + 512);
    };

    STAGE(0, 0);
    STAGE(1, 1);

    for (int kt = 0; kt < 32; ++kt) {
        if (kt < 30) STAGE((kt + 2) & 3, kt + 2);
        if (kt < 30)      { VMCNT(8); }
        else if (kt == 30){ VMCNT(4); }
        else              { VMCNT(0); }
        __builtin_amdgcn_s_barrier();

        const int cur = kt & 3;
        const unsigned short* KLc = &SH[cur * 4096];
        const unsigned short* VLc = &SH[16384 + cur * 4096];

        // K fragments (A-operand: lane l16 = kv row, k = ks*32+quad*8+j),
        // swizzled read: slot = (ks*4+quad) ^ (l16&7)
        bfrag kf[2][2];
#pragma unroll
        for (int ns = 0; ns < 2; ++ns) {
            const int r = (kh * 2 + ns) * 16 + l16;
#pragma unroll
            for (int ks = 0; ks < 2; ++ks)
                kf[ns][ks] = *(const bfrag*)(KLc + r * 64 + (((ks * 4 + quad) ^ (l16 & 7)) * 8));
        }
        // V fragments (row d = nb*16+l16, col kv-in-tile kh*32+ns*16+quad*4),
        // swizzle flips bits 3-5 of the shorts-offset (16B slots)
        bhalf4 vf[2][4];
#pragma unroll
        for (int nb = 0; nb < 4; ++nb) {
            const int d = nb * 16 + l16;
#pragma unroll
            for (int ns = 0; ns < 2; ++ns)
                vf[ns][nb] = *(const bhalf4*)(VLc + d * 64 +
                                ((kh * 32 + ns * 16 + quad * 4) ^ ((l16 & 7) * 8)));
        }

        const int fl = (int)((flbits >> kt) & 1u);
#pragma unroll
        for (int g = 0; g < 4; ++g) {
            // S^T = K Q^T (scale folded into Q): col=l16=q, row=quad*4+reg=kv
            ffrag st[2];
            __builtin_amdgcn_s_setprio(1);
#pragma unroll
            for (int ns = 0; ns < 2; ++ns) {
                ffrag a = (ffrag){0.f, 0.f, 0.f, 0.f};
                a = __builtin_amdgcn_mfma_f32_16x16x32_bf16(kf[ns][0], qf[g][0], a, 0, 0, 0);
                a = __builtin_amdgcn_mfma_f32_16x16x32_bf16(kf[ns][1], qf[g][1], a, 0, 0, 0);
                st[ns] = a;
            }
            __builtin_amdgcn_s_setprio(0);
            float p[2][4];
            if (fl) {
                const float* mrow = mask + ((size_t)b * T_ + q0 + rg * 64 + g * 16 + l16) * T_
                                  + kt * 64 + kh * 32 + quad * 4;
#pragma unroll
                for (int ns = 0; ns < 2; ++ns) {
                    float mv[4];
                    *(float4*)mv = *(const float4*)(mrow + ns * 16);
#pragma unroll
                    for (int reg = 0; reg < 4; ++reg)
                        p[ns][reg] = __builtin_amdgcn_exp2f(
                            fmaf(mv[reg], MASK_L2E, st[ns][reg] - MASK_L2E));
                }
            } else {
#pragma unroll
                for (int ns = 0; ns < 2; ++ns)
#pragma unroll
                    for (int reg = 0; reg < 4; ++reg)
                        p[ns][reg] = __builtin_amdgcn_exp2f(st[ns][reg]);
            }
            // pack P to bf16 in-register; ONE 32-K PV mfma per nb + ones-MFMA.
            // k = quad*8+j <-> kv = kh*32 + (j<4?0:16) + quad*4 + (j&3),
            // identical permutation on P (A) and V (B) (irrelevant for ones).
            union { unsigned int u[4]; bfrag s; } pa;
            pa.u[0] = cvt_pk_bf16(p[0][0], p[0][1]);
            pa.u[1] = cvt_pk_bf16(p[0][2], p[0][3]);
            pa.u[2] = cvt_pk_bf16(p[1][0], p[1][1]);
            pa.u[3] = cvt_pk_bf16(p[1][2], p[1][3]);
            __builtin_amdgcn_s_setprio(1);
#pragma unroll
            for (int nb = 0; nb < 4; ++nb) {
                union { bhalf4 h[2]; bfrag f; } vv;
                vv.h[0] = vf[0][nb];
                vv.h[1] = vf[1][nb];
                of[g][nb] = __builtin_amdgcn_mfma_f32_16x16x32_bf16(pa.s, vv.f, of[g][nb], 0, 0, 0);
            }
            of[g][4] = __builtin_amdgcn_mfma_f32_16x16x32_bf16(pa.s, vones, of[g][4], 0, 0, 0);
            __builtin_amdgcn_s_setprio(0);
        }
    }

    // ---------------- epilogue: combine kv halves, normalize, store --------
    __syncthreads();                   // full drain; everyone done with K/V LDS
    float* Fp = (float*)SH;            // 2 regions of 64*66 floats (per rg)
    // of[g][4][reg] = this wave's 32-kv partial row-sum for row quad*4+reg
    // (identical across l16) -> park per-kh in Rs.
    if (l16 == 0) {
#pragma unroll
        for (int g = 0; g < 4; ++g)
#pragma unroll
            for (int reg = 0; reg < 4; ++reg)
                Rs[kh * 128 + rg * 64 + g * 16 + quad * 4 + reg] = of[g][4][reg];
    }
    if (kh == 1) {                     // upper-kv waves park partial O in LDS
        float* basep = Fp + rg * (64 * 66);
#pragma unroll
        for (int g = 0; g < 4; ++g)
#pragma unroll
            for (int nb = 0; nb < 4; ++nb)
#pragma unroll
                for (int reg = 0; reg < 4; ++reg)
                    basep[(g * 16 + quad * 4 + reg) * 66 + nb * 16 + l16] = of[g][nb][reg];
    }
    __syncthreads();
    if (kh == 0) {                     // lower-kv waves: add, normalize, store
        const float* basep = Fp + rg * (64 * 66);
#pragma unroll
        for (int g = 0; g < 4; ++g) {
            float inv[4];
#pragma unroll
            for (int reg = 0; reg < 4; ++reg) {
                int row = rg * 64 + g * 16 + quad * 4 + reg;
                inv[reg] = 1.0f / (Rs[row] + Rs[128 + row]);
            }
#pragma unroll
            for (int nb = 0; nb < 4; ++nb)
#pragma unroll
                for (int reg = 0; reg < 4; ++reg) {
                    float v = of[g][nb][reg] + basep[(g * 16 + quad * 4 + reg) * 66 + nb * 16 + l16];
                    int t = q0 + rg * 64 + g * 16 + quad * 4 + reg;
                    out[((size_t)b * T_ + t) * DM_ + h * 64 + nb * 16 + l16] = v * inv[reg];
                }
        }
    }
}

// ---------------------------------------------------------------------------
extern "C" void kernel_launch(void* const* d_in, const int* in_sizes, int n_in,
                              void* d_out, int out_size, void* d_ws, size_t ws_size,
                              hipStream_t stream) {
    const float* X    = (const float*)d_in[0];   // [4,2048,512] fp32
    const float* mask = (const float*)d_in[1];   // [4,1,2048,2048] fp32
    const float* W    = (const float*)d_in[2];   // [512,1536] fp32
    const float* bias = (const float*)d_in[3];   // [1536] fp32
    float* outp = (float*)d_out;                 // [4,2048,512] fp32

    char* ws = (char*)d_ws;
    unsigned short* Wt  = (unsigned short*)(ws);              // 1.5 MB
    unsigned short* Xb  = (unsigned short*)(ws + 1572864);    // 8 MB
    unsigned short* Qb  = (unsigned short*)(ws + 9961472);    // 8 MB
    unsigned short* Kb  = (unsigned short*)(ws + 18350080);   // 8 MB
    unsigned short* Vtb = (unsigned short*)(ws + 26738688);   // 8 MB
    int*            flg = (int*)(ws + 35127296);              // 2 KB (no memset)

    k_prep     <<<dim3(448),  256, 0, stream>>>(W, X, Wt, Xb);
    k_gemm_qkv <<<dim3(1024), 256, 0, stream>>>(Xb, Wt, bias, Qb, Kb, Vtb, mask, flg);
    k_attn     <<<dim3(512),  256, 0, stream>>>(Qb, Kb, Vtb, mask, flg, outp);
}

// Round 15
// 182.516 us; speedup vs baseline: 1.0823x; 1.0823x over previous
//
#include <hip/hip_runtime.h>
#include <hip/hip_bf16.h>
#include <stdint.h>

#define B_   4
#define T_   2048
#define H_   8
#define HD_  64
#define DM_  512
#define N3_  1536

typedef short bf_el;
typedef __attribute__((ext_vector_type(8))) bf_el bfrag;   // 8 bf16 = 4 VGPRs
typedef __attribute__((ext_vector_type(4))) bf_el bhalf4;  // 4 bf16 = 2 VGPRs
typedef __attribute__((ext_vector_type(4))) float ffrag;

#define SCALE_L2E  0.18033688011112043f   /* 0.125 * log2(e) */
#define MASK_L2E   14426.950408889634f    /* 1e4  * log2(e) */

static __device__ __forceinline__ unsigned short f2bf(float f) {      // RNE
    union { float f; unsigned int i; } v; v.f = f;
    unsigned int r = v.i + 0x7fff + ((v.i >> 16) & 1);
    return (unsigned short)(r >> 16);
}
static __device__ __forceinline__ unsigned short f2bf_fast(float f) { // round-half-up
    union { float f; unsigned int i; } v; v.f = f;
    return (unsigned short)((v.i + 0x8000u) >> 16);
}

// pack 2 f32 -> 2 bf16 (RNE), lo16=a, hi16=b  [gfx950-verified: learn_hip m240]
static __device__ __forceinline__ unsigned int cvt_pk_bf16(float a, float b) {
    unsigned int r;
    asm("v_cvt_pk_bf16_f32 %0, %1, %2" : "=v"(r) : "v"(a), "v"(b));
    return r;
}

// async global->LDS, 16B per lane; LDS dest = wave-uniform base + lane*16
typedef __attribute__((address_space(1))) const unsigned int gu32;
typedef __attribute__((address_space(3))) unsigned int lu32;
static __device__ __forceinline__ void glds16(const unsigned short* g, unsigned short* l) {
    __builtin_amdgcn_global_load_lds((gu32*)g, (lu32*)l, 16, 0, 0);
}

// counted vmcnt wait (keeps newest N vm ops in flight) + scheduler fence
#define VMCNT(n) do { asm volatile("s_waitcnt vmcnt(" #n ")" ::: "memory"); \
                      __builtin_amdgcn_sched_barrier(0); } while (0)

// ---------------------------------------------------------------------------
// Kernel 0 (prep, 3 BW-bound roles by blockIdx.x):
//  [0,512)  : mask scan; flags = per-(b,qt64) x 4 quarter-words, each word's
//             byte w written EXCLUSIVELY by wave w of quarter-block (bid&3)
//             -> plain byte stores, NO atomics, NO pre-zero memset.
//  [512,768): X fp32 -> bf16
//  [768,960): W [512,1536] fp32 -> Wt bf16 [1536,512]
// ---------------------------------------------------------------------------
__global__ __launch_bounds__(256) void k_prep(const float* __restrict__ W,
                                              const float* __restrict__ X,
                                              const float* __restrict__ mask,
                                              unsigned short* __restrict__ Wt,
                                              unsigned short* __restrict__ Xb,
                                              int* __restrict__ flags) {
    __shared__ __align__(16) unsigned short Ls[64 * 72];
    const int bid = blockIdx.x;
    const int tid = threadIdx.x;

    if (bid < 512) {
        // ---- mask scan: 16 consecutive mask rows per block (128 KB) ----
        const int R0 = bid * 16;              // global row in [0, 8192)
        const int mb = R0 >> 11;              // batch
        const int q0 = R0 & 2047;
        const int e  = mb * 32 + (q0 >> 6);   // flag group (b*32 + qt64)
        const int wave = tid >> 6, lane = tid & 63;
        unsigned int acc = 0u;
        const float* base = mask + (size_t)R0 * T_ + tid * 8;
#pragma unroll
        for (int rr = 0; rr < 16; ++rr) {
            const uint4 u0 = *(const uint4*)(base + (size_t)rr * T_);
            const uint4 u1 = *(const uint4*)(base + (size_t)rr * T_ + 4);
            acc |= (u0.x ^ 0x3F800000u) | (u0.y ^ 0x3F800000u) |
                   (u0.z ^ 0x3F800000u) | (u0.w ^ 0x3F800000u) |
                   (u1.x ^ 0x3F800000u) | (u1.y ^ 0x3F800000u) |
                   (u1.z ^ 0x3F800000u) | (u1.w ^ 0x3F800000u);
        }
        unsigned long long bal = __ballot(acc != 0u);   // lane 8j..8j+7 = kt 8w+j
        if (lane == 0) {
            unsigned int byte = 0u;
#pragma unroll
            for (int j = 0; j < 8; ++j)
                if ((bal >> (8 * j)) & 0xFFULL) byte |= (1u << j);
            // word (e*4 + quarter), byte lane = wave  (bit kt = 8*wave + j)
            ((unsigned char*)flags)[((size_t)e * 4 + (bid & 3)) * 4 + wave] =
                (unsigned char)byte;
        }
        return;
    }
    if (bid < 768) {
        // ---- X convert: 16384 floats per block ----
        const int b2 = bid - 512;
        const float* src = X + (size_t)b2 * 16384;
        unsigned short* dst = Xb + (size_t)b2 * 16384;
#pragma unroll
        for (int j = 0; j < 8; ++j) {
            int idx = j * 512 + tid * 2;
            float4 f0 = *(const float4*)(src + idx * 4);
            float4 f1 = *(const float4*)(src + idx * 4 + 4);
            __align__(16) unsigned short t8[8];
            t8[0] = f2bf_fast(f0.x); t8[1] = f2bf_fast(f0.y);
            t8[2] = f2bf_fast(f0.z); t8[3] = f2bf_fast(f0.w);
            t8[4] = f2bf_fast(f1.x); t8[5] = f2bf_fast(f1.y);
            t8[6] = f2bf_fast(f1.z); t8[7] = f2bf_fast(f1.w);
            *(uint4*)(dst + idx * 4) = *(const uint4*)t8;
        }
        return;
    }
    // ---- W transpose+convert ----
    {
        const int t  = bid - 768;                 // 0..191 = 24 x 8
        const int n0 = (t % 24) * 64;
        const int k0 = (t / 24) * 64;
#pragma unroll
        for (int i = 0; i < 4; ++i) {
            int chunk = tid + i * 256;
            int k = chunk >> 4;
            int c = chunk & 15;
            float4 f = *(const float4*)(W + (size_t)(k0 + k) * N3_ + n0 + c * 4);
            unsigned short* p = Ls + k * 72 + c * 4;
            p[0] = f2bf(f.x); p[1] = f2bf(f.y); p[2] = f2bf(f.z); p[3] = f2bf(f.w);
        }
        __syncthreads();
        const int n = tid >> 2;
        const int g = tid & 3;
        __align__(16) unsigned short tmp[16];
#pragma unroll
        for (int i = 0; i < 16; ++i) tmp[i] = Ls[(g * 16 + i) * 72 + n];
        uint4* dst = (uint4*)(Wt + (size_t)(n0 + n) * DM_ + k0 + g * 16);
        dst[0] = *(const uint4*)(tmp);
        dst[1] = *(const uint4*)(tmp + 8);
    }
}

// ---------------------------------------------------------------------------
// Kernel 1: Xb bf16 [8192,512] @ Wt^T + bias -> Q(pre-scaled)/K/Vt bf16.
// 128(m) x 192(n) tile = one head. Flat grid bid = h*64 + mt so XCD = mt%8.
// K-loop uses the round-8-attn-PROVEN glds ring-4 counted-vmcnt schedule:
//   prologue STAGE(0),STAGE(1);
//   iter kt: STAGE((kt+2)&3) [kt<14]; VMCNT(10/5/0); s_barrier; read buf kt&3.
// 5 glds16/thread/STAGE (A:2, B:3) -> 15 outstanding; VMCNT(10) drains
// STAGE(kt). WAR: STAGE(kt+2) overwrites buf read at kt-2, issued after
// barrier(kt-1) which no wave passes before finishing kt-2 reads.
// LDS: linear A[128][32]+B[192][32] per buf (20KB), ring-4 = 80KB.
// Bank fix: 4-slot XOR swizzle (slot = quad ^ (row&3)) as pre-swizzled
// GLOBAL source + swizzled ds_read (same involution both sides).
// ---------------------------------------------------------------------------
__global__ __launch_bounds__(256) void k_gemm_qkv(const unsigned short* __restrict__ Xb,
                                                  const unsigned short* __restrict__ Wt,
                                                  const float* __restrict__ bias,
                                                  unsigned short* __restrict__ Qb,
                                                  unsigned short* __restrict__ Kb,
                                                  unsigned short* __restrict__ Vtb) {
    // ring-4: buf b at SH + b*10240 (A 4096 shorts, then B 6144 shorts).
    // epilogue Cs (64x200 = 12800 shorts) reuses the front.
    __shared__ __align__(16) unsigned short SH[40960];
    unsigned short* Cs = SH;            // row stride 200 shorts (192 data + 8 pad)

    const int tid  = threadIdx.x;
    const int wave = tid >> 6;
    const int lane = tid & 63;
    const int quad = lane >> 4;
    const int l16  = lane & 15;
    const int wm = wave >> 1, wn = wave & 1;    // 2x2 waves: 64 rows x 96 cols each
    const int h  = blockIdx.x >> 6;             // head
    const int m0 = (blockIdx.x & 63) * 128;
    const int n0 = h * 192;

    float bvv[6];
#pragma unroll
    for (int ni = 0; ni < 6; ++ni) bvv[ni] = bias[n0 + wn * 96 + ni * 16 + l16];

    ffrag acc[4][6];
#pragma unroll
    for (int i = 0; i < 4; ++i)
#pragma unroll
        for (int j = 0; j < 6; ++j) acc[i][j] = (ffrag){0.f, 0.f, 0.f, 0.f};

    // staging geometry: lane l covers local row lrow=l>>2 of a 16-row slab,
    // slot (l&3); global col16 is pre-swizzled: slot ^ (lrow&3).
    const int lrow = lane >> 2;
    const int gslot = (lane & 3) ^ (lrow & 3);
    const unsigned short* Ag = Xb + (size_t)(m0 + wave * 32 + lrow) * DM_ + gslot * 8;
    const unsigned short* Bg = Wt + (size_t)(n0 + wave * 48 + lrow) * DM_ + gslot * 8;

    auto STAGE = [&](int buf, int kt) {
        unsigned short* AL = SH + buf * 10240 + wave * 1024;
        unsigned short* BL = SH + buf * 10240 + 4096 + wave * 1536;
        const unsigned short* ag = Ag + kt * 32;
        const unsigned short* bg = Bg + kt * 32;
        glds16(ag, AL);
        glds16(ag + (size_t)16 * DM_, AL + 512);
        glds16(bg, BL);
        glds16(bg + (size_t)16 * DM_, BL + 512);
        glds16(bg + (size_t)32 * DM_, BL + 1024);
    };

    STAGE(0, 0);
    STAGE(1, 1);

    for (int kt = 0; kt < 16; ++kt) {
        if (kt < 14) STAGE((kt + 2) & 3, kt + 2);
        if (kt < 14)      { VMCNT(10); }
        else if (kt == 14){ VMCNT(5); }
        else              { VMCNT(0); }
        __builtin_amdgcn_s_barrier();

        const unsigned short* As = SH + (kt & 3) * 10240;
        const unsigned short* Bs = As + 4096;
        // swizzled reads: row R, want col16=quad -> slot = quad ^ (R&3),
        // R&3 == l16&3 for all fragment rows.
        const int rslot = (quad ^ (l16 & 3)) * 8;
        bfrag af[4], bfr[6];
#pragma unroll
        for (int mi = 0; mi < 4; ++mi)
            af[mi] = *(const bfrag*)(As + (wm * 64 + mi * 16 + l16) * 32 + rslot);
#pragma unroll
        for (int ni = 0; ni < 6; ++ni)
            bfr[ni] = *(const bfrag*)(Bs + (wn * 96 + ni * 16 + l16) * 32 + rslot);
        __builtin_amdgcn_s_setprio(1);
#pragma unroll
        for (int mi = 0; mi < 4; ++mi)
#pragma unroll
            for (int ni = 0; ni < 6; ++ni)
                acc[mi][ni] = __builtin_amdgcn_mfma_f32_16x16x32_bf16(af[mi], bfr[ni], acc[mi][ni], 0, 0, 0);
        __builtin_amdgcn_s_setprio(0);
    }

    // epilogue: two 64-row halves through Cs, coalesced uint4 stores.
    // Q columns (c%3==0) pre-scaled by 0.125*log2(e) so attn softmax is bare exp2.
    const int b   = m0 >> 11;
    const int tb0 = m0 & 2047;
    const size_t bh = (size_t)(b * 8 + h);
    float cscale[6];
#pragma unroll
    for (int ni = 0; ni < 6; ++ni) {
        int c = wn * 96 + ni * 16 + l16;
        cscale[ni] = (c % 3 == 0) ? SCALE_L2E : 1.0f;
    }
#pragma unroll
    for (int half = 0; half < 2; ++half) {
        __syncthreads();
        if (wm == half) {
#pragma unroll
            for (int mi = 0; mi < 4; ++mi)
#pragma unroll
                for (int ni = 0; ni < 6; ++ni)
#pragma unroll
                    for (int reg = 0; reg < 4; ++reg) {
                        int r = mi * 16 + quad * 4 + reg;          // 0..63 in half
                        int c = wn * 96 + ni * 16 + l16;           // 0..191
                        Cs[r * 200 + c] = f2bf_fast((acc[mi][ni][reg] + bvv[ni]) * cscale[ni]);
                    }
        }
        __syncthreads();
        const int tb = tb0 + half * 64;
#pragma unroll
        for (int i = 0; i < 2; ++i) {
            int idx = tid + i * 256;            // 0..511
            int tl = idx >> 3, hc = (idx & 7) * 8;
            __align__(16) unsigned short tq[8], tk[8];
#pragma unroll
            for (int j = 0; j < 8; ++j) {
                tq[j] = Cs[tl * 200 + (hc + j) * 3 + 0];
                tk[j] = Cs[tl * 200 + (hc + j) * 3 + 1];
            }
            *(uint4*)(Qb + (bh * T_ + tb + tl) * HD_ + hc) = *(const uint4*)tq;
            *(uint4*)(Kb + (bh * T_ + tb + tl) * HD_ + hc) = *(const uint4*)tk;
        }
#pragma unroll
        for (int i = 0; i < 2; ++i) {
            int idx = tid + i * 256;
            int hd = idx >> 3, t8 = (idx & 7) * 8;
            __align__(16) unsigned short tv[8];
#pragma unroll
            for (int j = 0; j < 8; ++j)
                tv[j] = Cs[(t8 + j) * 200 + hd * 3 + 2];
            *(uint4*)(Vtb + (bh * HD_ + hd) * T_ + tb + t8) = *(const uint4*)tv;
        }
    }
}

// ---------------------------------------------------------------------------
// Kernel 2: flash attention — EXACT round-8/12/13 structure (proven 3x):
// RING of 4 buffers (64 KB), distance-2 prefetch, counted vmcnt:
//   iter kt: STAGE((kt+2)&3, kt+2); vmcnt(8); s_barrier; read buf kt&3.
// ---------------------------------------------------------------------------
__global__ __launch_bounds__(256, 2) void k_attn(const unsigned short* __restrict__ Q,
                                                 const unsigned short* __restrict__ K,
                                                 const unsigned short* __restrict__ Vt,
                                                 const float* __restrict__ mask,
                                                 const int* __restrict__ flags,
                                                 float* __restrict__ out) {
    // [K buf0..3 | V buf0..3], each 64x64 shorts (8KB), linear. 64 KB total;
    // epilogue reuses the front as 2 x (64 x 66) float scratch (33.8 KB).
    __shared__ __align__(16) unsigned short SH[32768];
    __shared__ float Rs[256];           // row sums [kh][128]

    const int tid = threadIdx.x;
    const int wave = tid >> 6, lane = tid & 63;
    const int quad = lane >> 4, l16 = lane & 15;
    const int rg = wave & 1;        // row group: q rows rg*64 .. rg*64+63
    const int kh = wave >> 1;       // kv half:  kv kh*32 .. kh*32+31
    const int bh = blockIdx.x & 31, b = bh >> 3, h = bh & 7;
    const int qt = blockIdx.x >> 5;      // 0..15
    const int q0 = qt * 128;

    // Q fragments: 4 groups of 16 rows (B-operand of swapped QK^T:
    // lane l16 = q col, k = ks*32 + quad*8 + j)
    bfrag qf[4][2];
#pragma unroll
    for (int g = 0; g < 4; ++g) {
        size_t qrow = ((size_t)bh * T_ + q0 + rg * 64 + g * 16 + l16) * HD_;
        qf[g][0] = *(const bfrag*)(Q + qrow + quad * 8);
        qf[g][1] = *(const bfrag*)(Q + qrow + 32 + quad * 8);
    }
    // of[g][0..3] = O accumulators; of[g][4] = row-sum via ones-MFMA.
    ffrag of[4][5];
#pragma unroll
    for (int g = 0; g < 4; ++g)
#pragma unroll
        for (int nb = 0; nb < 5; ++nb) of[g][nb] = (ffrag){0.f, 0.f, 0.f, 0.f};

    bfrag vones;
#pragma unroll
    for (int j = 0; j < 8; ++j) vones[j] = (short)0x3F80;   // bf16 1.0

    // flags: OR the 4 quarter-words of this (b, 64-row block)
    const int e = b * 32 + qt * 2 + rg;
    const int4 fw = *(const int4*)(flags + (size_t)e * 4);
    const unsigned int flbits = (unsigned int)(fw.x | fw.y | fw.z | fw.w);

    // ---- staging geometry (glds, pre-swizzled source) ----
    const int lrow = lane >> 3, lcol = lane & 7, swz = lcol ^ lrow;
    const int voffK = lrow * 64 + swz * 8;                    // shorts in 8-row seg
    const size_t voffV = (size_t)(wave * 16 + lrow) * T_ + swz * 8;
    const unsigned short* Kbh = K  + (size_t)bh * T_ * HD_;   // + kt*4096 per tile
    const unsigned short* Vbh = Vt + (size_t)bh * HD_ * T_;   // + kt*64 per tile

    auto STAGE = [&](int buf, int kt) {
        unsigned short* KL = &SH[buf * 4096] + wave * 1024;
        unsigned short* VL = &SH[16384 + buf * 4096] + wave * 1024;
        const unsigned short* kg = Kbh + (size_t)kt * 4096 + wave * 1024 + voffK;
        const unsigned short* vg = Vbh + (size_t)kt * 64 + voffV;
        glds16(kg, KL);
        glds16(kg + 512, KL + 512);
        glds16(vg, VL);
        glds16(vg + (size_t)8 * T_, VL + 512);
    };

    STAGE(0, 0);
    STAGE(1, 1);

    for (int kt = 0; kt < 32; ++kt) {
        if (kt < 30) STAGE((kt + 2) & 3, kt + 2);
        if (kt < 30)      { VMCNT(8); }
        else if (kt == 30){ VMCNT(4); }
        else              { VMCNT(0); }
        __builtin_amdgcn_s_barrier();

        const int cur = kt & 3;
        const unsigned short* KLc = &SH[cur * 4096];
        const unsigned short* VLc = &SH[16384 + cur * 4096];

        // K fragments (A-operand: lane l16 = kv row, k = ks*32+quad*8+j),
        // swizzled read: slot = (ks*4+quad) ^ (l16&7)
        bfrag kf[2][2];
#pragma unroll
        for (int ns = 0; ns < 2; ++ns) {
            const int r = (kh * 2 + ns) * 16 + l16;
#pragma unroll
            for (int ks = 0; ks < 2; ++ks)
                kf[ns][ks] = *(const bfrag*)(KLc + r * 64 + (((ks * 4 + quad) ^ (l16 & 7)) * 8));
        }
        // V fragments (row d = nb*16+l16, col kv-in-tile kh*32+ns*16+quad*4),
        // swizzle flips bits 3-5 of the shorts-offset (16B slots)
        bhalf4 vf[2][4];
#pragma unroll
        for (int nb = 0; nb < 4; ++nb) {
            const int d = nb * 16 + l16;
#pragma unroll
            for (int ns = 0; ns < 2; ++ns)
                vf[ns][nb] = *(const bhalf4*)(VLc + d * 64 +
                                ((kh * 32 + ns * 16 + quad * 4) ^ ((l16 & 7) * 8)));
        }

        const int fl = (int)((flbits >> kt) & 1u);
#pragma unroll
        for (int g = 0; g < 4; ++g) {
            // S^T = K Q^T (scale folded into Q): col=l16=q, row=quad*4+reg=kv
            ffrag st[2];
            __builtin_amdgcn_s_setprio(1);
#pragma unroll
            for (int ns = 0; ns < 2; ++ns) {
                ffrag a = (ffrag){0.f, 0.f, 0.f, 0.f};
                a = __builtin_amdgcn_mfma_f32_16x16x32_bf16(kf[ns][0], qf[g][0], a, 0, 0, 0);
                a = __builtin_amdgcn_mfma_f32_16x16x32_bf16(kf[ns][1], qf[g][1], a, 0, 0, 0);
                st[ns] = a;
            }
            __builtin_amdgcn_s_setprio(0);
            float p[2][4];
            if (fl) {
                const float* mrow = mask + ((size_t)b * T_ + q0 + rg * 64 + g * 16 + l16) * T_
                                  + kt * 64 + kh * 32 + quad * 4;
#pragma unroll
                for (int ns = 0; ns < 2; ++ns) {
                    float mv[4];
                    *(float4*)mv = *(const float4*)(mrow + ns * 16);
#pragma unroll
                    for (int reg = 0; reg < 4; ++reg)
                        p[ns][reg] = __builtin_amdgcn_exp2f(
                            fmaf(mv[reg], MASK_L2E, st[ns][reg] - MASK_L2E));
                }
            } else {
#pragma unroll
                for (int ns = 0; ns < 2; ++ns)
#pragma unroll
                    for (int reg = 0; reg < 4; ++reg)
                        p[ns][reg] = __builtin_amdgcn_exp2f(st[ns][reg]);
            }
            // pack P to bf16 in-register; ONE 32-K PV mfma per nb + ones-MFMA.
            // k = quad*8+j <-> kv = kh*32 + (j<4?0:16) + quad*4 + (j&3),
            // identical permutation on P (A) and V (B) (irrelevant for ones).
            union { unsigned int u[4]; bfrag s; } pa;
            pa.u[0] = cvt_pk_bf16(p[0][0], p[0][1]);
            pa.u[1] = cvt_pk_bf16(p[0][2], p[0][3]);
            pa.u[2] = cvt_pk_bf16(p[1][0], p[1][1]);
            pa.u[3] = cvt_pk_bf16(p[1][2], p[1][3]);
            __builtin_amdgcn_s_setprio(1);
#pragma unroll
            for (int nb = 0; nb < 4; ++nb) {
                union { bhalf4 h[2]; bfrag f; } vv;
                vv.h[0] = vf[0][nb];
                vv.h[1] = vf[1][nb];
                of[g][nb] = __builtin_amdgcn_mfma_f32_16x16x32_bf16(pa.s, vv.f, of[g][nb], 0, 0, 0);
            }
            of[g][4] = __builtin_amdgcn_mfma_f32_16x16x32_bf16(pa.s, vones, of[g][4], 0, 0, 0);
            __builtin_amdgcn_s_setprio(0);
        }
    }

    // ---------------- epilogue: combine kv halves, normalize, store --------
    __syncthreads();                   // full drain; everyone done with K/V LDS
    float* Fp = (float*)SH;            // 2 regions of 64*66 floats (per rg)
    // of[g][4][reg] = this wave's 32-kv partial row-sum for row quad*4+reg
    // (identical across l16) -> park per-kh in Rs.
    if (l16 == 0) {
#pragma unroll
        for (int g = 0; g < 4; ++g)
#pragma unroll
            for (int reg = 0; reg < 4; ++reg)
                Rs[kh * 128 + rg * 64 + g * 16 + quad * 4 + reg] = of[g][4][reg];
    }
    if (kh == 1) {                     // upper-kv waves park partial O in LDS
        float* basep = Fp + rg * (64 * 66);
#pragma unroll
        for (int g = 0; g < 4; ++g)
#pragma unroll
            for (int nb = 0; nb < 4; ++nb)
#pragma unroll
                for (int reg = 0; reg < 4; ++reg)
                    basep[(g * 16 + quad * 4 + reg) * 66 + nb * 16 + l16] = of[g][nb][reg];
    }
    __syncthreads();
    if (kh == 0) {                     // lower-kv waves: add, normalize, store
        const float* basep = Fp + rg * (64 * 66);
#pragma unroll
        for (int g = 0; g < 4; ++g) {
            float inv[4];
#pragma unroll
            for (int reg = 0; reg < 4; ++reg) {
                int row = rg * 64 + g * 16 + quad * 4 + reg;
                inv[reg] = 1.0f / (Rs[row] + Rs[128 + row]);
            }
#pragma unroll
            for (int nb = 0; nb < 4; ++nb)
#pragma unroll
                for (int reg = 0; reg < 4; ++reg) {
                    float v = of[g][nb][reg] + basep[(g * 16 + quad * 4 + reg) * 66 + nb * 16 + l16];
                    int t = q0 + rg * 64 + g * 16 + quad * 4 + reg;
                    out[((size_t)b * T_ + t) * DM_ + h * 64 + nb * 16 + l16] = v * inv[reg];
                }
        }
    }
}

// ---------------------------------------------------------------------------
extern "C" void kernel_launch(void* const* d_in, const int* in_sizes, int n_in,
                              void* d_out, int out_size, void* d_ws, size_t ws_size,
                              hipStream_t stream) {
    const float* X    = (const float*)d_in[0];   // [4,2048,512] fp32
    const float* mask = (const float*)d_in[1];   // [4,1,2048,2048] fp32
    const float* W    = (const float*)d_in[2];   // [512,1536] fp32
    const float* bias = (const float*)d_in[3];   // [1536] fp32
    float* outp = (float*)d_out;                 // [4,2048,512] fp32

    char* ws = (char*)d_ws;
    unsigned short* Wt  = (unsigned short*)(ws);              // 1.5 MB
    unsigned short* Xb  = (unsigned short*)(ws + 1572864);    // 8 MB
    unsigned short* Qb  = (unsigned short*)(ws + 9961472);    // 8 MB
    unsigned short* Kb  = (unsigned short*)(ws + 18350080);   // 8 MB
    unsigned short* Vtb = (unsigned short*)(ws + 26738688);   // 8 MB
    int*            flg = (int*)(ws + 35127296);              // 2 KB (no memset)

    k_prep     <<<dim3(960), 256, 0, stream>>>(W, X, mask, Wt, Xb, flg);
    k_gemm_qkv <<<dim3(512), 256, 0, stream>>>(Xb, Wt, bias, Qb, Kb, Vtb);
    k_attn     <<<dim3(512), 256, 0, stream>>>(Qb, Kb, Vtb, mask, flg, outp);
}

// Round 16
// 181.089 us; speedup vs baseline: 1.0908x; 1.0079x over previous
//
#include <hip/hip_runtime.h>
#include <hip/hip_bf16.h>
#include <stdint.h>

#define B_   4
#define T_   2048
#define H_   8
#define HD_  64
#define DM_  512
#define N3_  1536

typedef short bf_el;
typedef __attribute__((ext_vector_type(8))) bf_el bfrag;   // 8 bf16 = 4 VGPRs
typedef __attribute__((ext_vector_type(4))) bf_el bhalf4;  // 4 bf16 = 2 VGPRs
typedef __attribute__((ext_vector_type(4))) float ffrag;

#define SCALE_L2E  0.18033688011112043f   /* 0.125 * log2(e) */
#define MASK_L2E   14426.950408889634f    /* 1e4  * log2(e) */

static __device__ __forceinline__ unsigned short f2bf(float f) {      // RNE
    union { float f; unsigned int i; } v; v.f = f;
    unsigned int r = v.i + 0x7fff + ((v.i >> 16) & 1);
    return (unsigned short)(r >> 16);
}
static __device__ __forceinline__ unsigned short f2bf_fast(float f) { // round-half-up
    union { float f; unsigned int i; } v; v.f = f;
    return (unsigned short)((v.i + 0x8000u) >> 16);
}

// pack 2 f32 -> 2 bf16 (RNE), lo16=a, hi16=b  [gfx950-verified: learn_hip m240]
static __device__ __forceinline__ unsigned int cvt_pk_bf16(float a, float b) {
    unsigned int r;
    asm("v_cvt_pk_bf16_f32 %0, %1, %2" : "=v"(r) : "v"(a), "v"(b));
    return r;
}

// async global->LDS, 16B per lane; LDS dest = wave-uniform base + lane*16
typedef __attribute__((address_space(1))) const unsigned int gu32;
typedef __attribute__((address_space(3))) unsigned int lu32;
static __device__ __forceinline__ void glds16(const unsigned short* g, unsigned short* l) {
    __builtin_amdgcn_global_load_lds((gu32*)g, (lu32*)l, 16, 0, 0);
}

// counted vmcnt wait (keeps newest N vm ops in flight) + scheduler fence
#define VMCNT(n) do { asm volatile("s_waitcnt vmcnt(" #n ")" ::: "memory"); \
                      __builtin_amdgcn_sched_barrier(0); } while (0)

// ---------------------------------------------------------------------------
// Kernel 0 (prep, 3 BW-bound roles by blockIdx.x):
//  [0,512)  : mask scan; flags = per-(b,qt64) x 4 quarter-words, each word's
//             byte w written EXCLUSIVELY by wave w of quarter-block (bid&3)
//             -> plain byte stores, NO atomics, NO pre-zero memset.
//  [512,768): X fp32 -> bf16
//  [768,960): W [512,1536] fp32 -> Wt bf16 [1536,512]
// ---------------------------------------------------------------------------
__global__ __launch_bounds__(256) void k_prep(const float* __restrict__ W,
                                              const float* __restrict__ X,
                                              const float* __restrict__ mask,
                                              unsigned short* __restrict__ Wt,
                                              unsigned short* __restrict__ Xb,
                                              int* __restrict__ flags) {
    __shared__ __align__(16) unsigned short Ls[64 * 72];
    const int bid = blockIdx.x;
    const int tid = threadIdx.x;

    if (bid < 512) {
        // ---- mask scan: 16 consecutive mask rows per block (128 KB) ----
        const int R0 = bid * 16;              // global row in [0, 8192)
        const int mb = R0 >> 11;              // batch
        const int q0 = R0 & 2047;
        const int e  = mb * 32 + (q0 >> 6);   // flag group (b*32 + qt64)
        const int wave = tid >> 6, lane = tid & 63;
        unsigned int acc = 0u;
        const float* base = mask + (size_t)R0 * T_ + tid * 8;
#pragma unroll
        for (int rr = 0; rr < 16; ++rr) {
            const uint4 u0 = *(const uint4*)(base + (size_t)rr * T_);
            const uint4 u1 = *(const uint4*)(base + (size_t)rr * T_ + 4);
            acc |= (u0.x ^ 0x3F800000u) | (u0.y ^ 0x3F800000u) |
                   (u0.z ^ 0x3F800000u) | (u0.w ^ 0x3F800000u) |
                   (u1.x ^ 0x3F800000u) | (u1.y ^ 0x3F800000u) |
                   (u1.z ^ 0x3F800000u) | (u1.w ^ 0x3F800000u);
        }
        unsigned long long bal = __ballot(acc != 0u);   // lane 8j..8j+7 = kt 8w+j
        if (lane == 0) {
            unsigned int byte = 0u;
#pragma unroll
            for (int j = 0; j < 8; ++j)
                if ((bal >> (8 * j)) & 0xFFULL) byte |= (1u << j);
            // word (e*4 + quarter), byte lane = wave  (bit kt = 8*wave + j)
            ((unsigned char*)flags)[((size_t)e * 4 + (bid & 3)) * 4 + wave] =
                (unsigned char)byte;
        }
        return;
    }
    if (bid < 768) {
        // ---- X convert: 16384 floats per block ----
        const int b2 = bid - 512;
        const float* src = X + (size_t)b2 * 16384;
        unsigned short* dst = Xb + (size_t)b2 * 16384;
#pragma unroll
        for (int j = 0; j < 8; ++j) {
            int idx = j * 512 + tid * 2;
            float4 f0 = *(const float4*)(src + idx * 4);
            float4 f1 = *(const float4*)(src + idx * 4 + 4);
            __align__(16) unsigned short t8[8];
            t8[0] = f2bf_fast(f0.x); t8[1] = f2bf_fast(f0.y);
            t8[2] = f2bf_fast(f0.z); t8[3] = f2bf_fast(f0.w);
            t8[4] = f2bf_fast(f1.x); t8[5] = f2bf_fast(f1.y);
            t8[6] = f2bf_fast(f1.z); t8[7] = f2bf_fast(f1.w);
            *(uint4*)(dst + idx * 4) = *(const uint4*)t8;
        }
        return;
    }
    // ---- W transpose+convert ----
    {
        const int t  = bid - 768;                 // 0..191 = 24 x 8
        const int n0 = (t % 24) * 64;
        const int k0 = (t / 24) * 64;
#pragma unroll
        for (int i = 0; i < 4; ++i) {
            int chunk = tid + i * 256;
            int k = chunk >> 4;
            int c = chunk & 15;
            float4 f = *(const float4*)(W + (size_t)(k0 + k) * N3_ + n0 + c * 4);
            unsigned short* p = Ls + k * 72 + c * 4;
            p[0] = f2bf(f.x); p[1] = f2bf(f.y); p[2] = f2bf(f.z); p[3] = f2bf(f.w);
        }
        __syncthreads();
        const int n = tid >> 2;
        const int g = tid & 3;
        __align__(16) unsigned short tmp[16];
#pragma unroll
        for (int i = 0; i < 16; ++i) tmp[i] = Ls[(g * 16 + i) * 72 + n];
        uint4* dst = (uint4*)(Wt + (size_t)(n0 + n) * DM_ + k0 + g * 16);
        dst[0] = *(const uint4*)(tmp);
        dst[1] = *(const uint4*)(tmp + 8);
    }
}

// ---------------------------------------------------------------------------
// Kernel 1: Xb bf16 [8192,512] @ Wt^T + bias -> Q(pre-scaled)/K/Vt bf16.
// 128(m) x 192(n) tile = one head. Flat grid bid = h*64 + mt so XCD = mt%8.
// Ring-4 glds counted-vmcnt schedule (proven r13/r15). setprio REMOVED:
// lockstep barrier structure = m190 regime where setprio is neutral/harmful.
// ---------------------------------------------------------------------------
__global__ __launch_bounds__(256) void k_gemm_qkv(const unsigned short* __restrict__ Xb,
                                                  const unsigned short* __restrict__ Wt,
                                                  const float* __restrict__ bias,
                                                  unsigned short* __restrict__ Qb,
                                                  unsigned short* __restrict__ Kb,
                                                  unsigned short* __restrict__ Vtb) {
    // ring-4: buf b at SH + b*10240 (A 4096 shorts, then B 6144 shorts).
    // epilogue Cs (64x200 = 12800 shorts) reuses the front.
    __shared__ __align__(16) unsigned short SH[40960];
    unsigned short* Cs = SH;            // row stride 200 shorts (192 data + 8 pad)

    const int tid  = threadIdx.x;
    const int wave = tid >> 6;
    const int lane = tid & 63;
    const int quad = lane >> 4;
    const int l16  = lane & 15;
    const int wm = wave >> 1, wn = wave & 1;    // 2x2 waves: 64 rows x 96 cols each
    const int h  = blockIdx.x >> 6;             // head
    const int m0 = (blockIdx.x & 63) * 128;
    const int n0 = h * 192;

    float bvv[6];
#pragma unroll
    for (int ni = 0; ni < 6; ++ni) bvv[ni] = bias[n0 + wn * 96 + ni * 16 + l16];

    ffrag acc[4][6];
#pragma unroll
    for (int i = 0; i < 4; ++i)
#pragma unroll
        for (int j = 0; j < 6; ++j) acc[i][j] = (ffrag){0.f, 0.f, 0.f, 0.f};

    // staging geometry: lane l covers local row lrow=l>>2 of a 16-row slab,
    // slot (l&3); global col16 is pre-swizzled: slot ^ (lrow&3).
    const int lrow = lane >> 2;
    const int gslot = (lane & 3) ^ (lrow & 3);
    const unsigned short* Ag = Xb + (size_t)(m0 + wave * 32 + lrow) * DM_ + gslot * 8;
    const unsigned short* Bg = Wt + (size_t)(n0 + wave * 48 + lrow) * DM_ + gslot * 8;

    auto STAGE = [&](int buf, int kt) {
        unsigned short* AL = SH + buf * 10240 + wave * 1024;
        unsigned short* BL = SH + buf * 10240 + 4096 + wave * 1536;
        const unsigned short* ag = Ag + kt * 32;
        const unsigned short* bg = Bg + kt * 32;
        glds16(ag, AL);
        glds16(ag + (size_t)16 * DM_, AL + 512);
        glds16(bg, BL);
        glds16(bg + (size_t)16 * DM_, BL + 512);
        glds16(bg + (size_t)32 * DM_, BL + 1024);
    };

    STAGE(0, 0);
    STAGE(1, 1);

    for (int kt = 0; kt < 16; ++kt) {
        if (kt < 14) STAGE((kt + 2) & 3, kt + 2);
        if (kt < 14)      { VMCNT(10); }
        else if (kt == 14){ VMCNT(5); }
        else              { VMCNT(0); }
        __builtin_amdgcn_s_barrier();

        const unsigned short* As = SH + (kt & 3) * 10240;
        const unsigned short* Bs = As + 4096;
        // swizzled reads: row R, want col16=quad -> slot = quad ^ (R&3),
        // R&3 == l16&3 for all fragment rows.
        const int rslot = (quad ^ (l16 & 3)) * 8;
        bfrag af[4], bfr[6];
#pragma unroll
        for (int mi = 0; mi < 4; ++mi)
            af[mi] = *(const bfrag*)(As + (wm * 64 + mi * 16 + l16) * 32 + rslot);
#pragma unroll
        for (int ni = 0; ni < 6; ++ni)
            bfr[ni] = *(const bfrag*)(Bs + (wn * 96 + ni * 16 + l16) * 32 + rslot);
#pragma unroll
        for (int mi = 0; mi < 4; ++mi)
#pragma unroll
            for (int ni = 0; ni < 6; ++ni)
                acc[mi][ni] = __builtin_amdgcn_mfma_f32_16x16x32_bf16(af[mi], bfr[ni], acc[mi][ni], 0, 0, 0);
    }

    // epilogue: two 64-row halves through Cs, coalesced uint4 stores.
    // Q columns (c%3==0) pre-scaled by 0.125*log2(e) so attn softmax is bare exp2.
    const int b   = m0 >> 11;
    const int tb0 = m0 & 2047;
    const size_t bh = (size_t)(b * 8 + h);
    float cscale[6];
#pragma unroll
    for (int ni = 0; ni < 6; ++ni) {
        int c = wn * 96 + ni * 16 + l16;
        cscale[ni] = (c % 3 == 0) ? SCALE_L2E : 1.0f;
    }
#pragma unroll
    for (int half = 0; half < 2; ++half) {
        __syncthreads();
        if (wm == half) {
#pragma unroll
            for (int mi = 0; mi < 4; ++mi)
#pragma unroll
                for (int ni = 0; ni < 6; ++ni)
#pragma unroll
                    for (int reg = 0; reg < 4; ++reg) {
                        int r = mi * 16 + quad * 4 + reg;          // 0..63 in half
                        int c = wn * 96 + ni * 16 + l16;           // 0..191
                        Cs[r * 200 + c] = f2bf_fast((acc[mi][ni][reg] + bvv[ni]) * cscale[ni]);
                    }
        }
        __syncthreads();
        const int tb = tb0 + half * 64;
#pragma unroll
        for (int i = 0; i < 2; ++i) {
            int idx = tid + i * 256;            // 0..511
            int tl = idx >> 3, hc = (idx & 7) * 8;
            __align__(16) unsigned short tq[8], tk[8];
#pragma unroll
            for (int j = 0; j < 8; ++j) {
                tq[j] = Cs[tl * 200 + (hc + j) * 3 + 0];
                tk[j] = Cs[tl * 200 + (hc + j) * 3 + 1];
            }
            *(uint4*)(Qb + (bh * T_ + tb + tl) * HD_ + hc) = *(const uint4*)tq;
            *(uint4*)(Kb + (bh * T_ + tb + tl) * HD_ + hc) = *(const uint4*)tk;
        }
#pragma unroll
        for (int i = 0; i < 2; ++i) {
            int idx = tid + i * 256;
            int hd = idx >> 3, t8 = (idx & 7) * 8;
            __align__(16) unsigned short tv[8];
#pragma unroll
            for (int j = 0; j < 8; ++j)
                tv[j] = Cs[(t8 + j) * 200 + hd * 3 + 2];
            *(uint4*)(Vtb + (bh * HD_ + hd) * T_ + tb + t8) = *(const uint4*)tv;
        }
    }
}

// ---------------------------------------------------------------------------
// Kernel 2: flash attention — round-8/12/13/15 structure (proven 4x):
// RING of 4 buffers (64 KB), distance-2 prefetch, counted vmcnt:
//   iter kt: STAGE((kt+2)&3, kt+2); vmcnt(8); s_barrier; read buf kt&3.
// setprio REMOVED (lockstep 4-wave barrier structure = m190 regime).
// ---------------------------------------------------------------------------
__global__ __launch_bounds__(256, 2) void k_attn(const unsigned short* __restrict__ Q,
                                                 const unsigned short* __restrict__ K,
                                                 const unsigned short* __restrict__ Vt,
                                                 const float* __restrict__ mask,
                                                 const int* __restrict__ flags,
                                                 float* __restrict__ out) {
    // [K buf0..3 | V buf0..3], each 64x64 shorts (8KB), linear. 64 KB total;
    // epilogue reuses the front as 2 x (64 x 66) float scratch (33.8 KB).
    __shared__ __align__(16) unsigned short SH[32768];
    __shared__ float Rs[256];           // row sums [kh][128]

    const int tid = threadIdx.x;
    const int wave = tid >> 6, lane = tid & 63;
    const int quad = lane >> 4, l16 = lane & 15;
    const int rg = wave & 1;        // row group: q rows rg*64 .. rg*64+63
    const int kh = wave >> 1;       // kv half:  kv kh*32 .. kh*32+31
    const int bh = blockIdx.x & 31, b = bh >> 3, h = bh & 7;
    const int qt = blockIdx.x >> 5;      // 0..15
    const int q0 = qt * 128;

    // Q fragments: 4 groups of 16 rows (B-operand of swapped QK^T:
    // lane l16 = q col, k = ks*32 + quad*8 + j)
    bfrag qf[4][2];
#pragma unroll
    for (int g = 0; g < 4; ++g) {
        size_t qrow = ((size_t)bh * T_ + q0 + rg * 64 + g * 16 + l16) * HD_;
        qf[g][0] = *(const bfrag*)(Q + qrow + quad * 8);
        qf[g][1] = *(const bfrag*)(Q + qrow + 32 + quad * 8);
    }
    // of[g][0..3] = O accumulators; of[g][4] = row-sum via ones-MFMA.
    ffrag of[4][5];
#pragma unroll
    for (int g = 0; g < 4; ++g)
#pragma unroll
        for (int nb = 0; nb < 5; ++nb) of[g][nb] = (ffrag){0.f, 0.f, 0.f, 0.f};

    bfrag vones;
#pragma unroll
    for (int j = 0; j < 8; ++j) vones[j] = (short)0x3F80;   // bf16 1.0

    // flags: OR the 4 quarter-words of this (b, 64-row block)
    const int e = b * 32 + qt * 2 + rg;
    const int4 fw = *(const int4*)(flags + (size_t)e * 4);
    const unsigned int flbits = (unsigned int)(fw.x | fw.y | fw.z | fw.w);

    // ---- staging geometry (glds, pre-swizzled source) ----
    const int lrow = lane >> 3, lcol = lane & 7, swz = lcol ^ lrow;
    const int voffK = lrow * 64 + swz * 8;                    // shorts in 8-row seg
    const size_t voffV = (size_t)(wave * 16 + lrow) * T_ + swz * 8;
    const unsigned short* Kbh = K  + (size_t)bh * T_ * HD_;   // + kt*4096 per tile
    const unsigned short* Vbh = Vt + (size_t)bh * HD_ * T_;   // + kt*64 per tile

    auto STAGE = [&](int buf, int kt) {
        unsigned short* KL = &SH[buf * 4096] + wave * 1024;
        unsigned short* VL = &SH[16384 + buf * 4096] + wave * 1024;
        const unsigned short* kg = Kbh + (size_t)kt * 4096 + wave * 1024 + voffK;
        const unsigned short* vg = Vbh + (size_t)kt * 64 + voffV;
        glds16(kg, KL);
        glds16(kg + 512, KL + 512);
        glds16(vg, VL);
        glds16(vg + (size_t)8 * T_, VL + 512);
    };

    STAGE(0, 0);
    STAGE(1, 1);

    for (int kt = 0; kt < 32; ++kt) {
        if (kt < 30) STAGE((kt + 2) & 3, kt + 2);
        if (kt < 30)      { VMCNT(8); }
        else if (kt == 30){ VMCNT(4); }
        else              { VMCNT(0); }
        __builtin_amdgcn_s_barrier();

        const int cur = kt & 3;
        const unsigned short* KLc = &SH[cur * 4096];
        const unsigned short* VLc = &SH[16384 + cur * 4096];

        // K fragments (A-operand: lane l16 = kv row, k = ks*32+quad*8+j),
        // swizzled read: slot = (ks*4+quad) ^ (l16&7)
        bfrag kf[2][2];
#pragma unroll
        for (int ns = 0; ns < 2; ++ns) {
            const int r = (kh * 2 + ns) * 16 + l16;
#pragma unroll
            for (int ks = 0; ks < 2; ++ks)
                kf[ns][ks] = *(const bfrag*)(KLc + r * 64 + (((ks * 4 + quad) ^ (l16 & 7)) * 8));
        }
        // V fragments (row d = nb*16+l16, col kv-in-tile kh*32+ns*16+quad*4),
        // swizzle flips bits 3-5 of the shorts-offset (16B slots)
        bhalf4 vf[2][4];
#pragma unroll
        for (int nb = 0; nb < 4; ++nb) {
            const int d = nb * 16 + l16;
#pragma unroll
            for (int ns = 0; ns < 2; ++ns)
                vf[ns][nb] = *(const bhalf4*)(VLc + d * 64 +
                                ((kh * 32 + ns * 16 + quad * 4) ^ ((l16 & 7) * 8)));
        }

        const int fl = (int)((flbits >> kt) & 1u);
#pragma unroll
        for (int g = 0; g < 4; ++g) {
            // S^T = K Q^T (scale folded into Q): col=l16=q, row=quad*4+reg=kv
            ffrag st[2];
#pragma unroll
            for (int ns = 0; ns < 2; ++ns) {
                ffrag a = (ffrag){0.f, 0.f, 0.f, 0.f};
                a = __builtin_amdgcn_mfma_f32_16x16x32_bf16(kf[ns][0], qf[g][0], a, 0, 0, 0);
                a = __builtin_amdgcn_mfma_f32_16x16x32_bf16(kf[ns][1], qf[g][1], a, 0, 0, 0);
                st[ns] = a;
            }
            float p[2][4];
            if (fl) {
                const float* mrow = mask + ((size_t)b * T_ + q0 + rg * 64 + g * 16 + l16) * T_
                                  + kt * 64 + kh * 32 + quad * 4;
#pragma unroll
                for (int ns = 0; ns < 2; ++ns) {
                    float mv[4];
                    *(float4*)mv = *(const float4*)(mrow + ns * 16);
#pragma unroll
                    for (int reg = 0; reg < 4; ++reg)
                        p[ns][reg] = __builtin_amdgcn_exp2f(
                            fmaf(mv[reg], MASK_L2E, st[ns][reg] - MASK_L2E));
                }
            } else {
#pragma unroll
                for (int ns = 0; ns < 2; ++ns)
#pragma unroll
                    for (int reg = 0; reg < 4; ++reg)
                        p[ns][reg] = __builtin_amdgcn_exp2f(st[ns][reg]);
            }
            // pack P to bf16 in-register; ONE 32-K PV mfma per nb + ones-MFMA.
            // k = quad*8+j <-> kv = kh*32 + (j<4?0:16) + quad*4 + (j&3),
            // identical permutation on P (A) and V (B) (irrelevant for ones).
            union { unsigned int u[4]; bfrag s; } pa;
            pa.u[0] = cvt_pk_bf16(p[0][0], p[0][1]);
            pa.u[1] = cvt_pk_bf16(p[0][2], p[0][3]);
            pa.u[2] = cvt_pk_bf16(p[1][0], p[1][1]);
            pa.u[3] = cvt_pk_bf16(p[1][2], p[1][3]);
#pragma unroll
            for (int nb = 0; nb < 4; ++nb) {
                union { bhalf4 h[2]; bfrag f; } vv;
                vv.h[0] = vf[0][nb];
                vv.h[1] = vf[1][nb];
                of[g][nb] = __builtin_amdgcn_mfma_f32_16x16x32_bf16(pa.s, vv.f, of[g][nb], 0, 0, 0);
            }
            of[g][4] = __builtin_amdgcn_mfma_f32_16x16x32_bf16(pa.s, vones, of[g][4], 0, 0, 0);
        }
    }

    // ---------------- epilogue: combine kv halves, normalize, store --------
    __syncthreads();                   // full drain; everyone done with K/V LDS
    float* Fp = (float*)SH;            // 2 regions of 64*66 floats (per rg)
    // of[g][4][reg] = this wave's 32-kv partial row-sum for row quad*4+reg
    // (identical across l16) -> park per-kh in Rs.
    if (l16 == 0) {
#pragma unroll
        for (int g = 0; g < 4; ++g)
#pragma unroll
            for (int reg = 0; reg < 4; ++reg)
                Rs[kh * 128 + rg * 64 + g * 16 + quad * 4 + reg] = of[g][4][reg];
    }
    if (kh == 1) {                     // upper-kv waves park partial O in LDS
        float* basep = Fp + rg * (64 * 66);
#pragma unroll
        for (int g = 0; g < 4; ++g)
#pragma unroll
            for (int nb = 0; nb < 4; ++nb)
#pragma unroll
                for (int reg = 0; reg < 4; ++reg)
                    basep[(g * 16 + quad * 4 + reg) * 66 + nb * 16 + l16] = of[g][nb][reg];
    }
    __syncthreads();
    if (kh == 0) {                     // lower-kv waves: add, normalize, store
        const float* basep = Fp + rg * (64 * 66);
#pragma unroll
        for (int g = 0; g < 4; ++g) {
            float inv[4];
#pragma unroll
            for (int reg = 0; reg < 4; ++reg) {
                int row = rg * 64 + g * 16 + quad * 4 + reg;
                inv[reg] = 1.0f / (Rs[row] + Rs[128 + row]);
            }
#pragma unroll
            for (int nb = 0; nb < 4; ++nb)
#pragma unroll
                for (int reg = 0; reg < 4; ++reg) {
                    float v = of[g][nb][reg] + basep[(g * 16 + quad * 4 + reg) * 66 + nb * 16 + l16];
                    int t = q0 + rg * 64 + g * 16 + quad * 4 + reg;
                    out[((size_t)b * T_ + t) * DM_ + h * 64 + nb * 16 + l16] = v * inv[reg];
                }
        }
    }
}

// ---------------------------------------------------------------------------
extern "C" void kernel_launch(void* const* d_in, const int* in_sizes, int n_in,
                              void* d_out, int out_size, void* d_ws, size_t ws_size,
                              hipStream_t stream) {
    const float* X    = (const float*)d_in[0];   // [4,2048,512] fp32
    const float* mask = (const float*)d_in[1];   // [4,1,2048,2048] fp32
    const float* W    = (const float*)d_in[2];   // [512,1536] fp32
    const float* bias = (const float*)d_in[3];   // [1536] fp32
    float* outp = (float*)d_out;                 // [4,2048,512] fp32

    char* ws = (char*)d_ws;
    unsigned short* Wt  = (unsigned short*)(ws);              // 1.5 MB
    unsigned short* Xb  = (unsigned short*)(ws + 1572864);    // 8 MB
    unsigned short* Qb  = (unsigned short*)(ws + 9961472);    // 8 MB
    unsigned short* Kb  = (unsigned short*)(ws + 18350080);   // 8 MB
    unsigned short* Vtb = (unsigned short*)(ws + 26738688);   // 8 MB
    int*            flg = (int*)(ws + 35127296);              // 2 KB (no memset)

    k_prep     <<<dim3(960), 256, 0, stream>>>(W, X, mask, Wt, Xb, flg);
    k_gemm_qkv <<<dim3(512), 256, 0, stream>>>(Xb, Wt, bias, Qb, Kb, Vtb);
    k_attn     <<<dim3(512), 256, 0, stream>>>(Qb, Kb, Vtb, mask, flg, outp);
}